// Round 10
// baseline (56.494 us; speedup 1.0000x reference)
//
#include <hip/hip_runtime.h>
#include <hip/hip_bf16.h>

// B=8, S=2048, D_MODEL=1024, D_K=D_V=64, causal, fp32 in/out.
// ws: Qb bf16[16384][64] | Kb bf16[16384][64] | Vt bf16[8][64][2048] | Wb bf16[192][1024]

typedef __attribute__((ext_vector_type(4))) float f32x4;
typedef __attribute__((ext_vector_type(8))) short short8;
typedef __attribute__((ext_vector_type(4))) short short4v;

#define MFMA16(a, b, c) __builtin_amdgcn_mfma_f32_16x16x32_bf16((a), (b), (c), 0, 0, 0)
#define SCHED_FENCE() __builtin_amdgcn_sched_barrier(0)

__device__ __forceinline__ unsigned short f2bf(float f) {
    unsigned int u = __float_as_uint(f);
    unsigned int r = (u + 0x7FFFu + ((u >> 16) & 1u)) >> 16;
    return (unsigned short)r;
}
// HW packed fp32->bf16 RNE (gfx950)
__device__ __forceinline__ unsigned int cvtpk2(float lo, float hi) {
    unsigned int r;
    asm("v_cvt_pk_bf16_f32 %0, %1, %2" : "=v"(r) : "v"(lo), "v"(hi));
    return r;
}
__device__ __forceinline__ f32x4 zero4() {
    f32x4 z = {0.f, 0.f, 0.f, 0.f};
    return z;
}
__device__ __forceinline__ void async16(const unsigned short* gsrc, unsigned short* ldst) {
    __builtin_amdgcn_global_load_lds(
        (const __attribute__((address_space(1))) unsigned int*)gsrc,
        (__attribute__((address_space(3))) unsigned int*)ldst, 16, 0, 0);
}

// ---------------------------------------------------------------------------
// Kernel 0: W_Q|W_K|W_V fp32[64][1024] -> Wb bf16[192][1024]
// ---------------------------------------------------------------------------
__global__ __launch_bounds__(256) void wconv(
    const float* __restrict__ wq, const float* __restrict__ wk,
    const float* __restrict__ wv, unsigned short* __restrict__ Wb)
{
    const int idx = (blockIdx.x * 256 + threadIdx.x) * 8;
    const int r = idx >> 10, c = idx & 1023;
    const float* src = (r < 64)  ? (wq + (long)r * 1024 + c)
                     : (r < 128) ? (wk + (long)(r - 64) * 1024 + c)
                     :             (wv + (long)(r - 128) * 1024 + c);
    f32x4 v0 = *(const f32x4*)src;
    f32x4 v1 = *(const f32x4*)(src + 4);
    short8 o;
    ((unsigned int*)&o)[0] = cvtpk2(v0[0], v0[1]);
    ((unsigned int*)&o)[1] = cvtpk2(v0[2], v0[3]);
    ((unsigned int*)&o)[2] = cvtpk2(v1[0], v1[1]);
    ((unsigned int*)&o)[3] = cvtpk2(v1[2], v1[3]);
    *(short8*)(Wb + idx) = o;
}

// ---------------------------------------------------------------------------
// Kernel 1: QKV GEMM. BM=32, BN=192, BK=64, dbuf LDS. Prefetch issue is
// PINNED above compute with sched_barrier(0) so the compiler cannot sink
// the loads to their use (R7 VGPR=64 proved it was doing exactly that);
// counted vmcnt(2) then leaves the A-loads in flight across the barrier.
// ---------------------------------------------------------------------------
__global__ __launch_bounds__(256, 2) void qkv_gemm(
    const float* __restrict__ x,
    const unsigned short* __restrict__ Wb,
    unsigned short* __restrict__ Qb,
    unsigned short* __restrict__ Kb,
    unsigned short* __restrict__ Vt)
{
    __shared__ __align__(16) unsigned short Blds[2][192 * 64];
    __shared__ __align__(16) unsigned short Alds[2][32 * 64];

    const int tid  = threadIdx.x;
    const int lane = tid & 63;
    const int wid  = tid >> 6;
    const int c16  = lane & 15;
    const int g    = lane >> 4;
    const long m0  = (long)blockIdx.x * 32;

    const int o0    = wid * 6144 + lane * 16;
    const int brow0 = o0 >> 7;
    const int boff0 = o0 & 127;
    const unsigned short* bsrc0 =
        Wb + (long)brow0 * 1024 + ((boff0 ^ ((brow0 & 7) << 4)) >> 1);

    const int ar  = tid >> 3, acq = tid & 7;
    const float* asrc = x + (m0 + ar) * 1024 + acq * 8;
    const int aoff = ar * 64 + (((acq * 16) ^ ((ar & 7) << 4)) >> 1);

    f32x4 acc[2][3];
    #pragma unroll
    for (int i = 0; i < 2; ++i)
        #pragma unroll
        for (int j = 0; j < 3; ++j) acc[i][j] = zero4();

    // ---- prologue: A(0)->LDS0 + B(0) asyncs + A(1)->regs ----
    f32x4 na0, na1;
    {
        f32x4 pa0 = *(const f32x4*)asrc;
        f32x4 pa1 = *(const f32x4*)(asrc + 4);
        #pragma unroll
        for (int i = 0; i < 6; ++i)
            async16(bsrc0 + i * 8192, &Blds[0][wid * 3072 + i * 512]);
        na0 = *(const f32x4*)(asrc + 64);
        na1 = *(const f32x4*)(asrc + 68);
        short8 p;
        ((unsigned int*)&p)[0] = cvtpk2(pa0[0], pa0[1]);
        ((unsigned int*)&p)[1] = cvtpk2(pa0[2], pa0[3]);
        ((unsigned int*)&p)[2] = cvtpk2(pa1[0], pa1[1]);
        ((unsigned int*)&p)[3] = cvtpk2(pa1[2], pa1[3]);
        *(short8*)&Alds[0][aoff] = p;
        asm volatile("s_waitcnt vmcnt(2)" ::: "memory");   // B(0) landed; A(1) flying
        asm volatile("s_waitcnt lgkmcnt(0)" ::: "memory");
        __builtin_amdgcn_s_barrier();
    }

    #pragma unroll 2
    for (int it = 0; it < 16; ++it) {
        const int cur = it & 1, nxt = cur ^ 1;
        // branchless prefetch (clamped at the edge: redundant, harmless)
        const int kb = min(it + 1, 15) * 64;
        #pragma unroll
        for (int i = 0; i < 6; ++i)
            async16(bsrc0 + kb + i * 8192, &Blds[nxt][wid * 3072 + i * 512]);
        const int ka = min(it + 2, 15) * 64;
        f32x4 qa0 = *(const f32x4*)(asrc + ka);
        f32x4 qa1 = *(const f32x4*)(asrc + ka + 4);
        SCHED_FENCE();   // pin prefetch issue ABOVE compute (no sinking)
        // ---- compute on cur ----
        #pragma unroll
        for (int kc = 0; kc < 2; ++kc) {
            const int q = kc * 64 + g * 16;
            short8 af[2], bf[3];
            #pragma unroll
            for (int mt = 0; mt < 2; ++mt) {
                const int rm = mt * 16 + c16;
                af[mt] = *(const short8*)&Alds[cur][rm * 64 + ((q ^ ((rm & 7) << 4)) >> 1)];
            }
            #pragma unroll
            for (int nt = 0; nt < 3; ++nt) {
                const int rb = wid * 48 + nt * 16 + c16;
                bf[nt] = *(const short8*)&Blds[cur][rb * 64 + ((q ^ ((rb & 7) << 4)) >> 1)];
            }
            __builtin_amdgcn_s_setprio(1);
            #pragma unroll
            for (int mt = 0; mt < 2; ++mt)
                #pragma unroll
                for (int nt = 0; nt < 3; ++nt)
                    acc[mt][nt] = MFMA16(af[mt], bf[nt], acc[mt][nt]);
            __builtin_amdgcn_s_setprio(0);
        }
        // ---- stage A(it+1) regs -> LDS(nxt); drain only the 6 B asyncs ----
        {
            short8 p;
            ((unsigned int*)&p)[0] = cvtpk2(na0[0], na0[1]);
            ((unsigned int*)&p)[1] = cvtpk2(na0[2], na0[3]);
            ((unsigned int*)&p)[2] = cvtpk2(na1[0], na1[1]);
            ((unsigned int*)&p)[3] = cvtpk2(na1[2], na1[3]);
            asm volatile("s_waitcnt vmcnt(2)" ::: "memory");   // 6 B done; 2 A flying
            *(short8*)&Alds[nxt][aoff] = p;
            asm volatile("s_waitcnt lgkmcnt(0)" ::: "memory");
            __builtin_amdgcn_s_barrier();
            na0 = qa0; na1 = qa1;
        }
    }

    // ---- epilogue: D layout col=c16, row=g*4+r ----
    const long bb = m0 >> 11;
    #pragma unroll
    for (int mt = 0; mt < 2; ++mt) {
        const long mrow = m0 + mt * 16 + g * 4;
        const long ss = mrow & 2047;
        #pragma unroll
        for (int nt = 0; nt < 3; ++nt) {
            const int n = wid * 48 + nt * 16 + c16;
            if (n < 64) {
                #pragma unroll
                for (int r = 0; r < 4; ++r)
                    Qb[(mrow + r) * 64 + n] = f2bf(acc[mt][nt][r]);
            } else if (n < 128) {
                #pragma unroll
                for (int r = 0; r < 4; ++r)
                    Kb[(mrow + r) * 64 + (n - 64)] = f2bf(acc[mt][nt][r]);
            } else {
                short4v pv = { (short)f2bf(acc[mt][nt][0]), (short)f2bf(acc[mt][nt][1]),
                               (short)f2bf(acc[mt][nt][2]), (short)f2bf(acc[mt][nt][3]) };
                *(short4v*)&Vt[((bb * 64) + (n - 128)) * 2048 + ss] = pv;
            }
        }
    }
}

// ---------------------------------------------------------------------------
// Kernel 2: causal attention. 32 q-rows per wave, swapped-QK^T, in-register
// P, no max tracking. Block = 8 waves on the causal pair {tA=pr, tB=63-pr};
// waves split between tiles prop. to cost. Depth-1 ping-pong prefetch is
// PINNED with sched_barrier(0) after each STEP_LOAD so the loads actually
// issue one step ahead (R7 VGPR=64 showed they were being sunk to use).
// PV slot map: A slot k=8g+j  <->  kv = kv0 + (j>>2)*16 + 4g + (j&3).
// ---------------------------------------------------------------------------
__global__ __launch_bounds__(512) void attn_fwd(
    const unsigned short* __restrict__ Qb,
    const unsigned short* __restrict__ Kb,
    const unsigned short* __restrict__ Vt,
    float* __restrict__ out)
{
    __shared__ __align__(16) float Obuf[8 * 16 * 64];   // 32KB, reused 2 passes
    __shared__ float lbuf[8 * 32];                      // [wave][qlocal]

    const int tid  = threadIdx.x;
    const int lane = tid & 63;
    const int wid  = tid >> 6;          // 0..7
    const int c16  = lane & 15;
    const int g    = lane >> 4;
    const int bidx = blockIdx.x;
    const int b    = bidx & 7;          // batch -> XCD (L2 locality)
    const int pr   = bidx >> 3;         // 0..31
    const int tA   = pr;
    const int tB   = 63 - pr;

    const int nbA = tA + 1;
    const int nbB = 64 - tA;            // nbA + nbB == 65
    int wA = (8 * nbA + 32) / 65;
    wA = max(1, min(7, wA));

    int q0, nb, nw, wi;
    if (wid < wA) { q0 = tA * 32; nb = nbA; nw = wA;     wi = wid; }
    else          { q0 = tB * 32; nb = nbB; nw = 8 - wA; wi = wid - wA; }
    const int cl  = (nb + nw - 1) / nw;
    const int blo = min(wi * cl, nb);
    const int bhi = min(blo + cl, nb);

    short8 qf[2][2];
    #pragma unroll
    for (int qg = 0; qg < 2; ++qg) {
        const unsigned short* qrow = Qb + ((long)b * 2048 + q0 + qg * 16 + c16) * 64;
        qf[qg][0] = *(const short8*)(qrow + g * 8);
        qf[qg][1] = *(const short8*)(qrow + 32 + g * 8);
    }
    const unsigned short* Kbase = Kb + (long)b * 2048 * 64;
    const unsigned short* Vbase = Vt + (long)b * 64 * 2048;

    f32x4 acc[2][4];
    #pragma unroll
    for (int qg = 0; qg < 2; ++qg)
        #pragma unroll
        for (int vt = 0; vt < 4; ++vt) acc[qg][vt] = zero4();
    f32x4 lp4[2];
    lp4[0] = zero4(); lp4[1] = zero4();

    const float SCL = 0.18033688f;   // log2(e)/8
    const int qgl[2] = { q0 + c16, q0 + 16 + c16 };

    short8 vfA[4], vfB[4];
    short8 kfA[2][2], kfB[2][2];

#define STEP_LOAD(KV0, VF, KF) do {                                            \
    const int _kv0 = (KV0);                                                    \
    _Pragma("unroll")                                                          \
    for (int vt = 0; vt < 4; ++vt) {                                           \
        const unsigned short* vrow =                                           \
            Vbase + (long)(vt * 16 + c16) * 2048 + _kv0 + 4 * g;               \
        ((short4v*)&VF[vt])[0] = *(const short4v*)vrow;                        \
        ((short4v*)&VF[vt])[1] = *(const short4v*)(vrow + 16);                 \
    }                                                                          \
    _Pragma("unroll")                                                          \
    for (int nt = 0; nt < 2; ++nt) {                                           \
        const unsigned short* krow =                                           \
            Kbase + (long)(_kv0 + nt * 16 + c16) * 64;                         \
        KF[nt][0] = *(const short8*)(krow + g * 8);                            \
        KF[nt][1] = *(const short8*)(krow + 32 + g * 8);                       \
    }                                                                          \
} while (0)

#define STEP_COMPUTE(KV0, VF, KF) do {                                         \
    const int _kv0 = (KV0);                                                    \
    f32x4 s[2][2];                                                             \
    __builtin_amdgcn_s_setprio(1);                                             \
    _Pragma("unroll")                                                          \
    for (int nt = 0; nt < 2; ++nt)                                             \
        _Pragma("unroll")                                                      \
        for (int qg = 0; qg < 2; ++qg) {                                       \
            f32x4 z = zero4();                                                 \
            z = MFMA16(KF[nt][0], qf[qg][0], z);                               \
            z = MFMA16(KF[nt][1], qf[qg][1], z);                               \
            s[qg][nt] = z;                                                     \
        }                                                                      \
    __builtin_amdgcn_s_setprio(0);                                             \
    short8 af[2];                                                              \
    _Pragma("unroll")                                                          \
    for (int qg = 0; qg < 2; ++qg) {                                           \
        _Pragma("unroll")                                                      \
        for (int nt = 0; nt < 2; ++nt) {                                       \
            float p[4];                                                        \
            _Pragma("unroll")                                                  \
            for (int r = 0; r < 4; ++r) {                                      \
                float v = exp2f(s[qg][nt][r] * SCL);                           \
                const int kvg = _kv0 + nt * 16 + g * 4 + r;                    \
                v = (kvg > qgl[qg]) ? 0.f : v;                                 \
                lp4[qg][r] += v;                                               \
                p[r] = v;                                                      \
            }                                                                  \
            ((unsigned int*)&af[qg])[nt * 2]     = cvtpk2(p[0], p[1]);         \
            ((unsigned int*)&af[qg])[nt * 2 + 1] = cvtpk2(p[2], p[3]);         \
        }                                                                      \
    }                                                                          \
    __builtin_amdgcn_s_setprio(1);                                             \
    _Pragma("unroll")                                                          \
    for (int qg = 0; qg < 2; ++qg)                                             \
        _Pragma("unroll")                                                      \
        for (int vt = 0; vt < 4; ++vt)                                         \
            acc[qg][vt] = MFMA16(af[qg], VF[vt], acc[qg][vt]);                 \
    __builtin_amdgcn_s_setprio(0);                                             \
} while (0)

    const int steps = bhi - blo;
    int blk = blo;
    if (steps > 0) {
        STEP_LOAD(blk * 32, vfA, kfA);
        SCHED_FENCE();
        int i = 0;
        for (; i + 2 <= steps; i += 2) {
            STEP_LOAD((blk + 1) * 32, vfB, kfB);      // unconditional: blk+1 < bhi
            SCHED_FENCE();                            // pin loads above compute
            STEP_COMPUTE(blk * 32, vfA, kfA);
            const int nn = min(blk + 2, bhi - 1);     // clamped: branchless
            STEP_LOAD(nn * 32, vfA, kfA);
            SCHED_FENCE();
            STEP_COMPUTE((blk + 1) * 32, vfB, kfB);
            blk += 2;
        }
        if (i < steps)
            STEP_COMPUTE(blk * 32, vfA, kfA);         // odd tail, already loaded
    }
#undef STEP_LOAD
#undef STEP_COMPUTE

    float lp[2];
    #pragma unroll
    for (int qg = 0; qg < 2; ++qg) {
        lp[qg] = (lp4[qg][0] + lp4[qg][1]) + (lp4[qg][2] + lp4[qg][3]);
        lp[qg] += __shfl_xor(lp[qg], 16);
        lp[qg] += __shfl_xor(lp[qg], 32);
    }
    if (g == 0) {
        lbuf[wid * 32 + c16]      = lp[0];
        lbuf[wid * 32 + 16 + c16] = lp[1];
    }

    // merge in two passes (qg = 0,1), Obuf holds one 16-row group at a time
    #pragma unroll
    for (int qg = 0; qg < 2; ++qg) {
        __syncthreads();
        #pragma unroll
        for (int vt = 0; vt < 4; ++vt)
            #pragma unroll
            for (int r = 0; r < 4; ++r)
                Obuf[(wid * 16 + g * 4 + r) * 64 + vt * 16 + c16] = acc[qg][vt][r];
        __syncthreads();

        const int tt  = tid >> 8;            // 0: tile A, 1: tile B
        const int row = (tid >> 4) & 15;
        const int c0  = (tid & 15) * 4;
        const int wlo = tt ? wA : 0;
        const int whi = tt ? 8  : wA;
        const int qrow = (tt ? tB : tA) * 32 + qg * 16 + row;

        float l = 0.f;
        for (int w = wlo; w < whi; ++w) l += lbuf[w * 32 + qg * 16 + row];
        const float inv = 1.0f / l;
        f32x4 o = zero4();
        for (int w = wlo; w < whi; ++w) {
            f32x4 t = *(const f32x4*)(Obuf + (w * 16 + row) * 64 + c0);
            #pragma unroll
            for (int j = 0; j < 4; ++j) o[j] += t[j];
        }
        #pragma unroll
        for (int j = 0; j < 4; ++j) o[j] *= inv;
        *(f32x4*)(out + ((long)b * 2048 + qrow) * 64 + c0) = o;
    }
}

extern "C" void kernel_launch(void* const* d_in, const int* in_sizes, int n_in,
                              void* d_out, int out_size, void* d_ws, size_t ws_size,
                              hipStream_t stream)
{
    const float* x  = (const float*)d_in[0];
    const float* wq = (const float*)d_in[1];
    const float* wk = (const float*)d_in[2];
    const float* wv = (const float*)d_in[3];

    unsigned short* Qb = (unsigned short*)d_ws;
    unsigned short* Kb = Qb + (size_t)16384 * 64;
    unsigned short* Vt = Kb + (size_t)16384 * 64;
    unsigned short* Wb = Vt + (size_t)8 * 64 * 2048;
    float* out = (float*)d_out;

    wconv<<<dim3(96), dim3(256), 0, stream>>>(wq, wk, wv, Wb);
    qkv_gemm<<<dim3(512), dim3(256), 0, stream>>>(x, Wb, Qb, Kb, Vt);
    attn_fwd<<<dim3(256), dim3(512), 0, stream>>>(Qb, Kb, Vt, out);
}

// Round 11
// 51.100 us; speedup vs baseline: 1.1056x; 1.1056x over previous
//
#include <hip/hip_runtime.h>
#include <hip/hip_bf16.h>

// B=8, S=2048, D_MODEL=1024, D_K=D_V=64, causal, fp32 in/out.
// ws (u16 units): Qb[16384*64] | Kb[16384*64] | Vt[8*64*2048] | Wb[192*1024]
//                | Opart u16[512*256*64] | Lpart f32[512*256]   (~24 MB total)

typedef __attribute__((ext_vector_type(4))) float f32x4;
typedef __attribute__((ext_vector_type(8))) short short8;
typedef __attribute__((ext_vector_type(4))) short short4v;

#define MFMA16(a, b, c) __builtin_amdgcn_mfma_f32_16x16x32_bf16((a), (b), (c), 0, 0, 0)

__device__ __forceinline__ unsigned short f2bf(float f) {
    unsigned int u = __float_as_uint(f);
    unsigned int r = (u + 0x7FFFu + ((u >> 16) & 1u)) >> 16;
    return (unsigned short)r;
}
__device__ __forceinline__ float bf2f(unsigned short u) {
    return __uint_as_float(((unsigned int)u) << 16);
}
__device__ __forceinline__ unsigned int cvtpk2(float lo, float hi) {
    unsigned int r;
    asm("v_cvt_pk_bf16_f32 %0, %1, %2" : "=v"(r) : "v"(lo), "v"(hi));
    return r;
}
__device__ __forceinline__ f32x4 zero4() {
    f32x4 z = {0.f, 0.f, 0.f, 0.f};
    return z;
}
__device__ __forceinline__ void async16(const unsigned short* gsrc, unsigned short* ldst) {
    __builtin_amdgcn_global_load_lds(
        (const __attribute__((address_space(1))) unsigned int*)gsrc,
        (__attribute__((address_space(3))) unsigned int*)ldst, 16, 0, 0);
}

// ---------------------------------------------------------------------------
// Kernel 0: W_Q|W_K|W_V fp32[64][1024] -> Wb bf16[192][1024]  (unchanged)
// ---------------------------------------------------------------------------
__global__ __launch_bounds__(256) void wconv(
    const float* __restrict__ wq, const float* __restrict__ wk,
    const float* __restrict__ wv, unsigned short* __restrict__ Wb)
{
    const int idx = (blockIdx.x * 256 + threadIdx.x) * 8;
    const int r = idx >> 10, c = idx & 1023;
    const float* src = (r < 64)  ? (wq + (long)r * 1024 + c)
                     : (r < 128) ? (wk + (long)(r - 64) * 1024 + c)
                     :             (wv + (long)(r - 128) * 1024 + c);
    f32x4 v0 = *(const f32x4*)src;
    f32x4 v1 = *(const f32x4*)(src + 4);
    short8 o;
    ((unsigned int*)&o)[0] = cvtpk2(v0[0], v0[1]);
    ((unsigned int*)&o)[1] = cvtpk2(v0[2], v0[3]);
    ((unsigned int*)&o)[2] = cvtpk2(v1[0], v1[1]);
    ((unsigned int*)&o)[3] = cvtpk2(v1[2], v1[3]);
    *(short8*)(Wb + idx) = o;
}

// ---------------------------------------------------------------------------
// Kernel 1: QKV GEMM (frozen from round 10).
// ---------------------------------------------------------------------------
__global__ __launch_bounds__(256, 2) void qkv_gemm(
    const float* __restrict__ x,
    const unsigned short* __restrict__ Wb,
    unsigned short* __restrict__ Qb,
    unsigned short* __restrict__ Kb,
    unsigned short* __restrict__ Vt)
{
    __shared__ __align__(16) unsigned short Blds[2][192 * 64];
    __shared__ __align__(16) unsigned short Alds[2][32 * 64];

    const int tid  = threadIdx.x;
    const int lane = tid & 63;
    const int wid  = tid >> 6;
    const int c16  = lane & 15;
    const int g    = lane >> 4;
    const long m0  = (long)blockIdx.x * 32;

    const int o0    = wid * 6144 + lane * 16;
    const int brow0 = o0 >> 7;
    const int boff0 = o0 & 127;
    const unsigned short* bsrc0 =
        Wb + (long)brow0 * 1024 + ((boff0 ^ ((brow0 & 7) << 4)) >> 1);

    const int ar  = tid >> 3, acq = tid & 7;
    const float* asrc = x + (m0 + ar) * 1024 + acq * 8;
    const int aoff = ar * 64 + (((acq * 16) ^ ((ar & 7) << 4)) >> 1);

    f32x4 acc[2][3];
    #pragma unroll
    for (int i = 0; i < 2; ++i)
        #pragma unroll
        for (int j = 0; j < 3; ++j) acc[i][j] = zero4();

    f32x4 na0, na1;
    {
        f32x4 pa0 = *(const f32x4*)asrc;
        f32x4 pa1 = *(const f32x4*)(asrc + 4);
        #pragma unroll
        for (int i = 0; i < 6; ++i)
            async16(bsrc0 + i * 8192, &Blds[0][wid * 3072 + i * 512]);
        na0 = *(const f32x4*)(asrc + 64);
        na1 = *(const f32x4*)(asrc + 68);
        short8 p;
        ((unsigned int*)&p)[0] = cvtpk2(pa0[0], pa0[1]);
        ((unsigned int*)&p)[1] = cvtpk2(pa0[2], pa0[3]);
        ((unsigned int*)&p)[2] = cvtpk2(pa1[0], pa1[1]);
        ((unsigned int*)&p)[3] = cvtpk2(pa1[2], pa1[3]);
        *(short8*)&Alds[0][aoff] = p;
        asm volatile("s_waitcnt vmcnt(2)" ::: "memory");
        asm volatile("s_waitcnt lgkmcnt(0)" ::: "memory");
        __builtin_amdgcn_s_barrier();
    }

    #pragma unroll 2
    for (int it = 0; it < 16; ++it) {
        const int cur = it & 1, nxt = cur ^ 1;
        const int kb = min(it + 1, 15) * 64;
        #pragma unroll
        for (int i = 0; i < 6; ++i)
            async16(bsrc0 + kb + i * 8192, &Blds[nxt][wid * 3072 + i * 512]);
        const int ka = min(it + 2, 15) * 64;
        f32x4 qa0 = *(const f32x4*)(asrc + ka);
        f32x4 qa1 = *(const f32x4*)(asrc + ka + 4);
        #pragma unroll
        for (int kc = 0; kc < 2; ++kc) {
            const int q = kc * 64 + g * 16;
            short8 af[2], bf[3];
            #pragma unroll
            for (int mt = 0; mt < 2; ++mt) {
                const int rm = mt * 16 + c16;
                af[mt] = *(const short8*)&Alds[cur][rm * 64 + ((q ^ ((rm & 7) << 4)) >> 1)];
            }
            #pragma unroll
            for (int nt = 0; nt < 3; ++nt) {
                const int rb = wid * 48 + nt * 16 + c16;
                bf[nt] = *(const short8*)&Blds[cur][rb * 64 + ((q ^ ((rb & 7) << 4)) >> 1)];
            }
            __builtin_amdgcn_s_setprio(1);
            #pragma unroll
            for (int mt = 0; mt < 2; ++mt)
                #pragma unroll
                for (int nt = 0; nt < 3; ++nt)
                    acc[mt][nt] = MFMA16(af[mt], bf[nt], acc[mt][nt]);
            __builtin_amdgcn_s_setprio(0);
        }
        {
            short8 p;
            ((unsigned int*)&p)[0] = cvtpk2(na0[0], na0[1]);
            ((unsigned int*)&p)[1] = cvtpk2(na0[2], na0[3]);
            ((unsigned int*)&p)[2] = cvtpk2(na1[0], na1[1]);
            ((unsigned int*)&p)[3] = cvtpk2(na1[2], na1[3]);
            asm volatile("s_waitcnt vmcnt(2)" ::: "memory");
            *(short8*)&Alds[nxt][aoff] = p;
            asm volatile("s_waitcnt lgkmcnt(0)" ::: "memory");
            __builtin_amdgcn_s_barrier();
            na0 = qa0; na1 = qa1;
        }
    }

    const long bb = m0 >> 11;
    #pragma unroll
    for (int mt = 0; mt < 2; ++mt) {
        const long mrow = m0 + mt * 16 + g * 4;
        const long ss = mrow & 2047;
        #pragma unroll
        for (int nt = 0; nt < 3; ++nt) {
            const int n = wid * 48 + nt * 16 + c16;
            if (n < 64) {
                #pragma unroll
                for (int r = 0; r < 4; ++r)
                    Qb[(mrow + r) * 64 + n] = f2bf(acc[mt][nt][r]);
            } else if (n < 128) {
                #pragma unroll
                for (int r = 0; r < 4; ++r)
                    Kb[(mrow + r) * 64 + (n - 64)] = f2bf(acc[mt][nt][r]);
            } else {
                short4v pv = { (short)f2bf(acc[mt][nt][0]), (short)f2bf(acc[mt][nt][1]),
                               (short)f2bf(acc[mt][nt][2]), (short)f2bf(acc[mt][nt][3]) };
                *(short4v*)&Vt[((bb * 64) + (n - 128)) * 2048 + ss] = pv;
            }
        }
    }
}

// ---------------------------------------------------------------------------
// Kernel 2a: attention partials, LOCKSTEP shared-KV structure.
// Unit = (batch, super-tile T of 256 q-rows, kv-eighth e): T in 0..7, e in
// 0..7, steps = T+1 kv32-blocks starting at e*(T+1). Block = 8 waves x 32
// q-rows, all marching the same kv; K[32][64] and V^T[64][32] staged once
// per step into dbuf LDS via global_load_lds with pre-swizzled sources
// (K: ^((row&7)<<4) [m201 pattern], V: ^((row&6)<<3), both 16B-granular).
// Pairing {(T,e),(7-T,7-e)} -> 9 uniform steps/block, grid 256 = 1/CU.
// Partials: O as bf16, l as f32, merged by attn_merge.
// ---------------------------------------------------------------------------
__global__ __launch_bounds__(512) void attn_part(
    const unsigned short* __restrict__ Qb,
    const unsigned short* __restrict__ Kb,
    const unsigned short* __restrict__ Vt,
    unsigned short* __restrict__ Opart,
    float* __restrict__ Lpart)
{
    __shared__ __align__(16) unsigned short Klds[2][32 * 64];   // 4KB each
    __shared__ __align__(16) unsigned short Vlds[2][64 * 32];   // 4KB each

    const int tid  = threadIdx.x;
    const int lane = tid & 63;
    const int wid  = tid >> 6;          // 0..7
    const int c16  = lane & 15;
    const int g    = lane >> 4;
    const int b    = blockIdx.x & 7;    // batch -> XCD
    const int pr   = blockIdx.x >> 3;   // 0..31
    const int TA   = pr >> 3;           // 0..3
    const int eA   = pr & 7;

    const unsigned short* Qbase = Qb + (long)b * 2048 * 64;
    const unsigned short* Kbase = Kb + (long)b * 2048 * 64;
    const unsigned short* Vbase = Vt + (long)b * 64 * 2048;

    const float SCL = 0.18033688f;      // log2(e)/8

    // wave-uniform staging constants
    const int krow  = (wid < 4) ? ((wid << 3) + (lane >> 3)) : 0;
    const int kboff = (lane & 7) * 16;
    const int vj    = (wid >= 4) ? (((wid - 4) << 6) + lane) : 0;
    const int vrow  = vj >> 2;
    const int vboff = (vj & 3) * 16;

    #pragma unroll 1
    for (int ph = 0; ph < 2; ++ph) {
        const int T     = ph ? 7 - TA : TA;
        const int e     = ph ? 7 - eA : eA;
        const int steps = T + 1;
        const int kvb0  = e * steps;
        const int q0w   = T * 256 + wid * 32;
        const int u     = (b * 8 + T) * 8 + e;

        // Q fragments (B-operand): rows q0w + qg*16 + c16
        short8 qf[2][2];
        #pragma unroll
        for (int qg = 0; qg < 2; ++qg) {
            const unsigned short* qrow = Qbase + (long)(q0w + qg * 16 + c16) * 64;
            qf[qg][0] = *(const short8*)(qrow + g * 8);
            qf[qg][1] = *(const short8*)(qrow + 32 + g * 8);
        }
        const int qgl0 = q0w + c16;
        const int qgl1 = q0w + 16 + c16;

        f32x4 acc[2][4];
        #pragma unroll
        for (int qg = 0; qg < 2; ++qg)
            #pragma unroll
            for (int vt = 0; vt < 4; ++vt) acc[qg][vt] = zero4();
        f32x4 lp4[2];
        lp4[0] = zero4(); lp4[1] = zero4();

        // ---- stage step 0 into buf 0 ----
        {
            const int kv0s = kvb0 * 32;
            if (wid < 4)
                async16(Kbase + (long)(kv0s + krow) * 64 + ((kboff ^ ((krow & 7) << 4)) >> 1),
                        &Klds[0][wid * 512]);
            else
                async16(Vbase + (long)vrow * 2048 + kv0s + ((vboff ^ ((vrow & 6) << 3)) >> 1),
                        &Vlds[0][(wid - 4) * 512]);
        }
        asm volatile("s_waitcnt vmcnt(0)" ::: "memory");
        __builtin_amdgcn_s_barrier();

        int cur = 0;
        for (int s = 0; s < steps; ++s) {
            // ---- stage next step into other buffer (clamped at edge) ----
            {
                const int kv0s = (kvb0 + min(s + 1, steps - 1)) * 32;
                if (wid < 4)
                    async16(Kbase + (long)(kv0s + krow) * 64 + ((kboff ^ ((krow & 7) << 4)) >> 1),
                            &Klds[cur ^ 1][wid * 512]);
                else
                    async16(Vbase + (long)vrow * 2048 + kv0s + ((vboff ^ ((vrow & 6) << 3)) >> 1),
                            &Vlds[cur ^ 1][(wid - 4) * 512]);
            }
            const int kv0 = (kvb0 + s) * 32;

            // ---- V fragments from LDS (swizzled) ----
            short8 vf[4];
            #pragma unroll
            for (int vt = 0; vt < 4; ++vt) {
                const int row = vt * 16 + c16;
                const char* vr = (const char*)&Vlds[cur][row * 32];
                const int x = (row & 6) << 3;
                short4v lo = *(const short4v*)(vr + ((8 * g) ^ x));
                short4v hi = *(const short4v*)(vr + ((32 + 8 * g) ^ x));
                ((short4v*)&vf[vt])[0] = lo;
                ((short4v*)&vf[vt])[1] = hi;
            }
            // ---- K fragments + QK^T (swapped) ----
            f32x4 s2[2][2];
            #pragma unroll
            for (int nt = 0; nt < 2; ++nt) {
                const int row = nt * 16 + c16;
                const char* kr = (const char*)&Klds[cur][row * 64];
                const int x = (row & 7) << 4;
                short8 kf0 = *(const short8*)(kr + ((g * 16) ^ x));
                short8 kf1 = *(const short8*)(kr + ((64 + g * 16) ^ x));
                __builtin_amdgcn_s_setprio(1);
                #pragma unroll
                for (int qg = 0; qg < 2; ++qg) {
                    f32x4 z = zero4();
                    z = MFMA16(kf0, qf[qg][0], z);
                    z = MFMA16(kf1, qf[qg][1], z);
                    s2[qg][nt] = z;
                }
                __builtin_amdgcn_s_setprio(0);
            }
            // ---- p = exp(s/8), causal mask, pack A-frags ----
            short8 af[2];
            #pragma unroll
            for (int qg = 0; qg < 2; ++qg) {
                const int qgl = qg ? qgl1 : qgl0;
                #pragma unroll
                for (int nt = 0; nt < 2; ++nt) {
                    float p[4];
                    #pragma unroll
                    for (int r = 0; r < 4; ++r) {
                        float v = exp2f(s2[qg][nt][r] * SCL);
                        const int kvg = kv0 + nt * 16 + g * 4 + r;
                        v = (kvg > qgl) ? 0.f : v;
                        lp4[qg][r] += v;
                        p[r] = v;
                    }
                    ((unsigned int*)&af[qg])[nt * 2]     = cvtpk2(p[0], p[1]);
                    ((unsigned int*)&af[qg])[nt * 2 + 1] = cvtpk2(p[2], p[3]);
                }
            }
            // ---- PV ----
            __builtin_amdgcn_s_setprio(1);
            #pragma unroll
            for (int qg = 0; qg < 2; ++qg)
                #pragma unroll
                for (int vt = 0; vt < 4; ++vt)
                    acc[qg][vt] = MFMA16(af[qg], vf[vt], acc[qg][vt]);
            __builtin_amdgcn_s_setprio(0);

            asm volatile("s_waitcnt vmcnt(0)" ::: "memory");  // next stage landed
            __builtin_amdgcn_s_barrier();
            cur ^= 1;
        }

        // ---- epilogue: l reduce + partial writes ----
        float lpf[2];
        #pragma unroll
        for (int qg = 0; qg < 2; ++qg) {
            lpf[qg] = (lp4[qg][0] + lp4[qg][1]) + (lp4[qg][2] + lp4[qg][3]);
            lpf[qg] += __shfl_xor(lpf[qg], 16);
            lpf[qg] += __shfl_xor(lpf[qg], 32);
        }
        if (g == 0) {
            Lpart[u * 256 + wid * 32 + c16]      = lpf[0];
            Lpart[u * 256 + wid * 32 + 16 + c16] = lpf[1];
        }
        #pragma unroll
        for (int qg = 0; qg < 2; ++qg)
            #pragma unroll
            for (int vt = 0; vt < 4; ++vt)
                #pragma unroll
                for (int r = 0; r < 4; ++r) {
                    const int row = wid * 32 + qg * 16 + g * 4 + r;
                    Opart[((long)u * 256 + row) * 64 + vt * 16 + c16] =
                        f2bf(acc[qg][vt][r]);
                }
        // loop's trailing barrier synced all waves; epilogue is global-only,
        // next phase re-stages after its own vmcnt+barrier.
        __builtin_amdgcn_s_barrier();
    }
}

// ---------------------------------------------------------------------------
// Kernel 2b: merge 8 kv-eighth partials per row, normalize, write out.
// Block m: batch = m&7 (XCD-matched to where partials were written),
// 32 rows x 8 col-groups per block.
// ---------------------------------------------------------------------------
__global__ __launch_bounds__(256) void attn_merge(
    const unsigned short* __restrict__ Opart,
    const float* __restrict__ Lpart,
    float* __restrict__ out)
{
    const int m    = blockIdx.x;          // 0..511
    const int bb   = m & 7;
    const int part = m >> 3;              // 0..63
    const int t    = threadIdx.x;
    const int lr   = part * 32 + (t >> 3);   // batch-local row
    const int c8   = t & 7;                  // 8-col group
    const int T    = lr >> 8, ri = lr & 255;
    const int ub   = (bb * 8 + T) * 8;

    float o[8];
    #pragma unroll
    for (int j = 0; j < 8; ++j) o[j] = 0.f;
    float l = 0.f;
    #pragma unroll
    for (int e = 0; e < 8; ++e) {
        const unsigned short* Op = Opart + ((long)(ub + e) * 256 + ri) * 64 + c8 * 8;
        short4v p0 = *(const short4v*)Op;
        short4v p1 = *(const short4v*)(Op + 4);
        #pragma unroll
        for (int j = 0; j < 4; ++j) {
            o[j]     += bf2f((unsigned short)p0[j]);
            o[4 + j] += bf2f((unsigned short)p1[j]);
        }
        l += Lpart[(ub + e) * 256 + ri];
    }
    const float inv = 1.0f / l;
    f32x4 o0 = { o[0] * inv, o[1] * inv, o[2] * inv, o[3] * inv };
    f32x4 o1 = { o[4] * inv, o[5] * inv, o[6] * inv, o[7] * inv };
    float* orow = out + ((long)bb * 2048 + lr) * 64 + c8 * 8;
    *(f32x4*)orow = o0;
    *(f32x4*)(orow + 4) = o1;
}

extern "C" void kernel_launch(void* const* d_in, const int* in_sizes, int n_in,
                              void* d_out, int out_size, void* d_ws, size_t ws_size,
                              hipStream_t stream)
{
    const float* x  = (const float*)d_in[0];
    const float* wq = (const float*)d_in[1];
    const float* wk = (const float*)d_in[2];
    const float* wv = (const float*)d_in[3];

    unsigned short* Qb    = (unsigned short*)d_ws;
    unsigned short* Kb    = Qb + (size_t)16384 * 64;
    unsigned short* Vt    = Kb + (size_t)16384 * 64;
    unsigned short* Wb    = Vt + (size_t)8 * 64 * 2048;
    unsigned short* Opart = Wb + (size_t)192 * 1024;
    float*          Lpart = (float*)(Opart + (size_t)512 * 256 * 64);
    float* out = (float*)d_out;

    wconv<<<dim3(96), dim3(256), 0, stream>>>(wq, wk, wv, Wb);
    qkv_gemm<<<dim3(512), dim3(256), 0, stream>>>(x, Wb, Qb, Kb, Vt);
    attn_part<<<dim3(256), dim3(512), 0, stream>>>(Qb, Kb, Vt, Opart, Lpart);
    attn_merge<<<dim3(512), dim3(256), 0, stream>>>(Opart, Lpart, out);
}